// Round 4
// baseline (314.740 us; speedup 1.0000x reference)
//
#include <hip/hip_runtime.h>
#include <math.h>

#define BB   1024
#define DD   768
#define HIDV 384
#define MLPH 300
#define MLPP 320   // padded to multiple of 64

typedef float v2f __attribute__((ext_vector_type(2)));

__device__ __forceinline__ float softplusf(float x) {
    return (x > 20.f) ? x : log1pf(expf(x));
}

__device__ __forceinline__ void f4arr(float4 v, float* o) {
    o[0] = v.x; o[1] = v.y; o[2] = v.z; o[3] = v.w;
}

// ---------------- init: zero accumulators (accum[16] + sumexp[1024]) ----------------
__global__ void k_init(float* __restrict__ ws) {
    int i = blockIdx.x * 256 + threadIdx.x;
    if (i < 16 + BB) ws[i] = 0.f;
}

// ---------------- A: fused z-reduce + sample + KL partial ----------------
// 512 blocks x 2 CONSECUTIVE rows: each block streams a 2x-longer contiguous
// region (fewer concurrent DRAM streams) and each thread owns two
// independent load streams (2x memory-level parallelism).
__global__ __launch_bounds__(192, 4) void k_rs(
    const float* __restrict__ zl, const float* __restrict__ zv,
    const float* __restrict__ wl, const float* __restrict__ blp,
    const float* __restrict__ wv, const float* __restrict__ bvp,
    const float* __restrict__ eps1, const float* __restrict__ eps2,
    float* __restrict__ s1, float* __restrict__ s2, float* __restrict__ accum)
{
    int b0 = blockIdx.x * 2;
    int t = threadIdx.x;               // 0..191
    const float4* zlA = (const float4*)zl + b0 * (20 * 192) + t;
    const float4* zlB = zlA + 20 * 192;
    const float4* zvA = (const float4*)zv + b0 * (36 * 192) + t;
    const float4* zvB = zvA + 36 * 192;

    float z1a[4] = {0,0,0,0}, z1b[4] = {0,0,0,0};
    float z2a[4] = {0,0,0,0}, z2b[4] = {0,0,0,0};

    #pragma unroll
    for (int s = 0; s < 20; ++s) {
        float w = wl[s];
        float a[4], c[4];
        f4arr(zlA[s * 192], a);
        f4arr(zlB[s * 192], c);
        #pragma unroll
        for (int j = 0; j < 4; ++j) {
            z1a[j] = fmaf(a[j], w, z1a[j]);
            z1b[j] = fmaf(c[j], w, z1b[j]);
        }
    }
    #pragma unroll
    for (int s = 0; s < 36; ++s) {
        float w = wv[s];
        float a[4], c[4];
        f4arr(zvA[s * 192], a);
        f4arr(zvB[s * 192], c);
        #pragma unroll
        for (int j = 0; j < 4; ++j) {
            z2a[j] = fmaf(a[j], w, z2a[j]);
            z2b[j] = fmaf(c[j], w, z2b[j]);
        }
    }

    float bl = blp[0], bv = bvp[0];

    __shared__ __align__(16) float sg1s[2][HIDV];
    __shared__ __align__(16) float sg2s[2][HIDV];

    if (t >= 96) {
        int u = t - 96;
        float o1[4], o2[4];
        #pragma unroll
        for (int j = 0; j < 4; ++j) {
            o1[j] = softplusf(z1a[j] + bl) + 1e-7f;
            o2[j] = softplusf(z2a[j] + bv) + 1e-7f;
        }
        ((float4*)sg1s[0])[u] = make_float4(o1[0], o1[1], o1[2], o1[3]);
        ((float4*)sg2s[0])[u] = make_float4(o2[0], o2[1], o2[2], o2[3]);
        #pragma unroll
        for (int j = 0; j < 4; ++j) {
            o1[j] = softplusf(z1b[j] + bl) + 1e-7f;
            o2[j] = softplusf(z2b[j] + bv) + 1e-7f;
        }
        ((float4*)sg1s[1])[u] = make_float4(o1[0], o1[1], o1[2], o1[3]);
        ((float4*)sg2s[1])[u] = make_float4(o2[0], o2[1], o2[2], o2[3]);
    }
    __syncthreads();

    float con = 0.f;
    if (t < 96) {
        #pragma unroll
        for (int rr = 0; rr < 2; ++rr) {
            int b = b0 + rr;
            const float* zm1 = rr ? z1b : z1a;
            const float* zm2 = rr ? z2b : z2a;
            float e1v[4], e2v[4], g1[4], g2[4];
            f4arr(((const float4*)eps1)[b * 96 + t], e1v);
            f4arr(((const float4*)eps2)[b * 96 + t], e2v);
            f4arr(((const float4*)sg1s[rr])[t], g1);
            f4arr(((const float4*)sg2s[rr])[t], g2);
            float s1o[4], s2o[4];
            #pragma unroll
            for (int j = 0; j < 4; ++j) {
                float mu1 = zm1[j] + bl;
                float mu2 = zm2[j] + bv;
                float sg1 = g1[j], sg2 = g2[j];
                float e1 = e1v[j], e2 = e2v[j];
                float sv1 = fmaf(sg1, e1, mu1);
                float sv2 = fmaf(sg2, e2, mu2);
                s1o[j] = sv1; s2o[j] = sv2;
                float z12 = (sv1 - mu2) / sg2;
                float z21 = (sv2 - mu1) / sg1;
                con += -0.5f * (e1 * e1 + e2 * e2) + 0.5f * z12 * z12 + 0.5f * z21 * z21;
            }
            ((float4*)s1)[b * 96 + t] = make_float4(s1o[0], s1o[1], s1o[2], s1o[3]);
            ((float4*)s2)[b * 96 + t] = make_float4(s2o[0], s2o[1], s2o[2], s2o[3]);
        }
    }

    #pragma unroll
    for (int m = 1; m < 64; m <<= 1) con += __shfl_xor(con, m);
    __shared__ float pr[3];
    if ((t & 63) == 0) pr[t >> 6] = con;
    __syncthreads();
    if (t == 0) atomicAdd(&accum[0], pr[0] + pr[1] + pr[2]);
}

// ---------------- B: Axb = s1 @ W1x^T + b1 (padded), By = s2 @ W1y^T ----------------
// 32x64 tiles -> 320 blocks; packed <2 x float> math for v_pk_fma_f32.
__global__ __launch_bounds__(256) void k_gemm(
    const float* __restrict__ s1, const float* __restrict__ s2,
    const float* __restrict__ W1, const float* __restrict__ b1,
    float* __restrict__ Axb, float* __restrict__ By)
{
    __shared__ __align__(16) float Ss[32][36];   // [h][b] 32x32
    __shared__ __align__(16) float Ws[32][68];   // [h][k] 32x64
    int z = blockIdx.z;
    const float* S = z ? s2 : s1;
    float* Out = z ? By : Axb;
    int wofs = z ? HIDV : 0;
    int b0 = blockIdx.x * 32;
    int k0 = blockIdx.y * 64;
    int tid = threadIdx.x;
    int srow = tid >> 3, sc = tid & 7;       // S staging: 32 rows x 8 col-groups
    int wrow = tid >> 2, wc = tid & 3;       // W staging: 64 rows x 4 col-groups (x2)
    int krow = k0 + wrow;
    int tx = tid & 15, ty = tid >> 4;

    float4 ps, pw[2];
    auto ld = [&](int hc) {
        ps = *(const float4*)&S[(b0 + srow) * HIDV + hc + sc * 4];
        #pragma unroll
        for (int u = 0; u < 2; ++u)
            pw[u] = (krow < MLPH) ? *(const float4*)&W1[krow * DD + wofs + hc + wc * 4 + u * 16]
                                  : make_float4(0.f, 0.f, 0.f, 0.f);
    };
    ld(0);
    v2f acc[2][2];
    acc[0][0] = (v2f){0.f, 0.f}; acc[0][1] = (v2f){0.f, 0.f};
    acc[1][0] = (v2f){0.f, 0.f}; acc[1][1] = (v2f){0.f, 0.f};

    for (int ch = 0; ch < 12; ++ch) {
        __syncthreads();
        Ss[sc * 4 + 0][srow] = ps.x; Ss[sc * 4 + 1][srow] = ps.y;
        Ss[sc * 4 + 2][srow] = ps.z; Ss[sc * 4 + 3][srow] = ps.w;
        #pragma unroll
        for (int u = 0; u < 2; ++u) {
            int hb = wc * 4 + u * 16;
            Ws[hb + 0][wrow] = pw[u].x; Ws[hb + 1][wrow] = pw[u].y;
            Ws[hb + 2][wrow] = pw[u].z; Ws[hb + 3][wrow] = pw[u].w;
        }
        __syncthreads();
        if (ch < 11) ld((ch + 1) * 32);
        #pragma unroll
        for (int h = 0; h < 32; ++h) {
            v2f sv = *(const v2f*)&Ss[h][ty * 2];
            float4 wq = *(const float4*)&Ws[h][tx * 4];
            v2f w0 = (v2f){wq.x, wq.y};
            v2f w1 = (v2f){wq.z, wq.w};
            v2f s0 = (v2f){sv.x, sv.x};
            v2f s1b = (v2f){sv.y, sv.y};
            acc[0][0] = __builtin_elementwise_fma(s0, w0, acc[0][0]);
            acc[0][1] = __builtin_elementwise_fma(s0, w1, acc[0][1]);
            acc[1][0] = __builtin_elementwise_fma(s1b, w0, acc[1][0]);
            acc[1][1] = __builtin_elementwise_fma(s1b, w1, acc[1][1]);
        }
    }
    #pragma unroll
    for (int i = 0; i < 2; ++i) {
        int bb = b0 + ty * 2 + i;
        float vraw[4] = {acc[i][0].x, acc[i][0].y, acc[i][1].x, acc[i][1].y};
        float o[4];
        #pragma unroll
        for (int j = 0; j < 4; ++j) {
            int k = k0 + tx * 4 + j;
            float v = vraw[j];
            if (!z) v += b1[k < MLPH ? k : 0];
            o[j] = (k < MLPH) ? v : 0.f;
        }
        *(float4*)&Out[bb * MLPP + k0 + tx * 4] = make_float4(o[0], o[1], o[2], o[3]);
    }
}

// ---------------- C: T0 sum ----------------
__global__ void k_t0(const float* __restrict__ Axb, const float* __restrict__ By,
                     const float* __restrict__ W2, const float* __restrict__ b2,
                     float* __restrict__ accum)
{
    int b = blockIdx.x;
    int l = threadIdx.x;  // 64
    float t = 0.f;
    for (int k = l; k < MLPH; k += 64)
        t = fmaf(fmaxf(Axb[b * MLPP + k] + By[b * MLPP + k], 0.f), W2[k], t);
    #pragma unroll
    for (int m = 1; m < 64; m <<= 1) t += __shfl_xor(t, m);
    if (l == 0) atomicAdd(&accum[1], softplusf(t + b2[0]));
}

// ---------------- D: pair kernel, packed math, fused sumexp(T1) ----------------
__global__ __launch_bounds__(256) void k_pairs(
    const float* __restrict__ Axb, const float* __restrict__ By,
    const int* __restrict__ perm, const float* __restrict__ W2,
    const float* __restrict__ b2, float* __restrict__ sumexp)
{
    __shared__ __align__(16) float As[64][68];   // [k][j]
    __shared__ __align__(16) float Bs[64][68];   // [k][i]
    __shared__ float w2s[MLPP];
    int tid = threadIdx.x;
    int j0 = blockIdx.x * 64;
    int i0 = blockIdx.y * 64;
    for (int t = tid; t < MLPP; t += 256) w2s[t] = (t < MLPH) ? W2[t] : 0.f;
    int r = tid >> 2;          // 0..63
    int c4 = tid & 3;
    int tx = tid & 15, ty = tid >> 4;
    int prow = perm[i0 + r];

    float4 pa[4], pb[4];
    auto ld = [&](int kc) {
        #pragma unroll
        for (int u = 0; u < 4; ++u) {
            int kq = (c4 + 4 * u) * 4;   // 0..60
            pa[u] = *(const float4*)&Axb[(j0 + r) * MLPP + kc + kq];
            pb[u] = *(const float4*)&By[prow * MLPP + kc + kq];
        }
    };
    ld(0);
    v2f acc2[4][2];
    #pragma unroll
    for (int c = 0; c < 4; ++c) {
        acc2[c][0] = (v2f){0.f, 0.f};
        acc2[c][1] = (v2f){0.f, 0.f};
    }
    for (int ch = 0; ch < 5; ++ch) {
        __syncthreads();
        #pragma unroll
        for (int u = 0; u < 4; ++u) {
            int kq = (c4 + 4 * u) * 4;
            As[kq + 0][r] = pa[u].x; As[kq + 1][r] = pa[u].y;
            As[kq + 2][r] = pa[u].z; As[kq + 3][r] = pa[u].w;
            Bs[kq + 0][r] = pb[u].x; Bs[kq + 1][r] = pb[u].y;
            Bs[kq + 2][r] = pb[u].z; Bs[kq + 3][r] = pb[u].w;
        }
        __syncthreads();
        if (ch < 4) ld((ch + 1) * 64);
        int kc = ch * 64;
        #pragma unroll
        for (int k = 0; k < 64; ++k) {
            float w = w2s[kc + k];
            v2f wv2 = (v2f){w, w};
            float4 af = *(const float4*)&As[k][tx * 4];
            float4 bf = *(const float4*)&Bs[k][ty * 4];
            v2f a2[2] = { (v2f){af.x, af.y}, (v2f){af.z, af.w} };
            float bs[4] = {bf.x, bf.y, bf.z, bf.w};
            #pragma unroll
            for (int c = 0; c < 4; ++c) {
                v2f bc = (v2f){bs[c], bs[c]};
                #pragma unroll
                for (int d2 = 0; d2 < 2; ++d2) {
                    v2f tv = a2[d2] + bc;
                    tv = __builtin_elementwise_max(tv, (v2f){0.f, 0.f});
                    acc2[c][d2] = __builtin_elementwise_fma(tv, wv2, acc2[c][d2]);
                }
            }
        }
    }
    float b2v = b2[0];
    #pragma unroll
    for (int c = 0; c < 4; ++c) {
        float vv[4] = {acc2[c][0].x, acc2[c][0].y, acc2[c][1].x, acc2[c][1].y};
        float ssum = 0.f;
        #pragma unroll
        for (int d = 0; d < 4; ++d)
            ssum += 1.f + expf(vv[d] + b2v);   // exp(softplus(x)) == 1 + exp(x)
        ssum += __shfl_xor(ssum, 1);
        ssum += __shfl_xor(ssum, 2);
        ssum += __shfl_xor(ssum, 4);
        ssum += __shfl_xor(ssum, 8);
        if (tx == 0) atomicAdd(&sumexp[i0 + ty * 4 + c], ssum);
    }
}

// ---------------- E: final scalar ----------------
__global__ __launch_bounds__(256) void k_final(
    const float* __restrict__ accum, const float* __restrict__ sumexp,
    float* __restrict__ out)
{
    int tid = threadIdx.x;
    float s = 0.f;
    for (int i = tid; i < BB; i += 256) s += logf(sumexp[i]);
    #pragma unroll
    for (int m = 1; m < 64; m <<= 1) s += __shfl_xor(s, m);
    __shared__ float red[4];
    if ((tid & 63) == 0) red[tid >> 6] = s;
    __syncthreads();
    if (tid == 0) {
        float lse_mean = (red[0] + red[1] + red[2] + red[3]) / (float)BB;
        float d_skl = accum[0] / (2.f * (float)BB);
        float t0_mean = accum[1] / (float)BB;
        float lower = t0_mean - (lse_mean - logf((float)BB));
        out[0] = d_skl - lower;
    }
}

extern "C" void kernel_launch(void* const* d_in, const int* in_sizes, int n_in,
                              void* d_out, int out_size, void* d_ws, size_t ws_size,
                              hipStream_t stream)
{
    const float* zl     = (const float*)d_in[0];
    const float* zv     = (const float*)d_in[1];
    const float* fc_l_w = (const float*)d_in[2];
    const float* fc_l_b = (const float*)d_in[3];
    const float* fc_v_w = (const float*)d_in[4];
    const float* fc_v_b = (const float*)d_in[5];
    const float* W1     = (const float*)d_in[6];
    const float* b1     = (const float*)d_in[7];
    const float* W2     = (const float*)d_in[8];
    const float* b2     = (const float*)d_in[9];
    const float* eps1   = (const float*)d_in[10];
    const float* eps2   = (const float*)d_in[11];
    const int*   perm   = (const int*)d_in[12];
    float* out = (float*)d_out;

    float* ws     = (float*)d_ws;
    float* accum  = ws;                    // 16
    float* sumexp = ws + 16;               // 1024
    float* s1     = ws + 16 + BB;          // B*384
    float* s2     = s1 + BB * HIDV;        // B*384
    float* Axb    = s2 + BB * HIDV;        // B*320
    float* By     = Axb + BB * MLPP;       // B*320

    k_init<<<5, 256, 0, stream>>>(ws);
    k_rs<<<BB / 2, 192, 0, stream>>>(zl, zv, fc_l_w, fc_l_b, fc_v_w, fc_v_b,
                                     eps1, eps2, s1, s2, accum);
    k_gemm<<<dim3(32, 5, 2), 256, 0, stream>>>(s1, s2, W1, b1, Axb, By);
    k_t0<<<BB, 64, 0, stream>>>(Axb, By, W2, b2, accum);
    k_pairs<<<dim3(16, 16), 256, 0, stream>>>(Axb, By, perm, W2, b2, sumexp);
    k_final<<<1, 256, 0, stream>>>(accum, sumexp, out);
}

// Round 5
// 312.623 us; speedup vs baseline: 1.0068x; 1.0068x over previous
//
#include <hip/hip_runtime.h>
#include <math.h>

#define BB   1024
#define DD   768
#define HIDV 384
#define MLPH 300
#define MLPP 320   // padded to multiple of 64

typedef float v2f __attribute__((ext_vector_type(2)));

__device__ __forceinline__ float softplusf(float x) {
    return (x > 20.f) ? x : log1pf(expf(x));
}

__device__ __forceinline__ void f4arr(float4 v, float* o) {
    o[0] = v.x; o[1] = v.y; o[2] = v.z; o[3] = v.w;
}

// ---------------- init: zero accumulators (accum[16] + sumexp[1024]) ----------------
__global__ void k_init(float* __restrict__ ws) {
    int i = blockIdx.x * 256 + threadIdx.x;
    if (i < 16 + BB) ws[i] = 0.f;
}

// ---------------- A: fused z-reduce + sample + KL partial ----------------
// One block (384 threads, 6 waves) per batch row. Thread (half, col) reduces
// HALF the s-range for float4 column col; halves combine via LDS. Twice the
// waves of r3 (24/CU possible) with half the loads each -> tests whether k_rs
// is latency-bound (drops to ~50us) or pattern-capped (stays ~70us).
__global__ __launch_bounds__(384, 6) void k_rs(
    const float* __restrict__ zl, const float* __restrict__ zv,
    const float* __restrict__ wl, const float* __restrict__ blp,
    const float* __restrict__ wv, const float* __restrict__ bvp,
    const float* __restrict__ eps1, const float* __restrict__ eps2,
    float* __restrict__ s1, float* __restrict__ s2, float* __restrict__ accum)
{
    int b = blockIdx.x;
    int t = threadIdx.x;               // 0..383
    int half = (t >= 192) ? 1 : 0;
    int col = t - half * 192;          // 0..191
    int ofl = half * 10;               // zl s-offset
    int ofv = half * 18;               // zv s-offset
    const float4* zl4 = (const float4*)zl + b * (20 * 192) + ofl * 192 + col;
    const float4* zv4 = (const float4*)zv + b * (36 * 192) + ofv * 192 + col;

    float z1v[4] = {0,0,0,0}, z2v[4] = {0,0,0,0};

    #pragma unroll
    for (int sp = 0; sp < 10; ++sp) {
        float w = wl[sp + ofl];
        float a[4];
        f4arr(zl4[sp * 192], a);
        #pragma unroll
        for (int j = 0; j < 4; ++j) z1v[j] = fmaf(a[j], w, z1v[j]);
    }
    #pragma unroll
    for (int sp = 0; sp < 18; ++sp) {
        float w = wv[sp + ofv];
        float a[4];
        f4arr(zv4[sp * 192], a);
        #pragma unroll
        for (int j = 0; j < 4; ++j) z2v[j] = fmaf(a[j], w, z2v[j]);
    }

    // combine half-1 partials into half-0 threads via LDS
    __shared__ __align__(16) float p1[192 * 4];
    __shared__ __align__(16) float p2[192 * 4];
    if (half) {
        ((float4*)p1)[col] = make_float4(z1v[0], z1v[1], z1v[2], z1v[3]);
        ((float4*)p2)[col] = make_float4(z2v[0], z2v[1], z2v[2], z2v[3]);
    }
    __syncthreads();
    if (!half) {
        float q1[4], q2[4];
        f4arr(((const float4*)p1)[col], q1);
        f4arr(((const float4*)p2)[col], q2);
        #pragma unroll
        for (int j = 0; j < 4; ++j) { z1v[j] += q1[j]; z2v[j] += q2[j]; }
    }

    float bl = blp[0], bv = bvp[0];

    __shared__ __align__(16) float sg1s[HIDV];  // softplus(z1_sig)+eps
    __shared__ __align__(16) float sg2s[HIDV];

    if (!half && col >= 96) {
        float o1[4], o2[4];
        #pragma unroll
        for (int j = 0; j < 4; ++j) {
            o1[j] = softplusf(z1v[j] + bl) + 1e-7f;
            o2[j] = softplusf(z2v[j] + bv) + 1e-7f;
        }
        ((float4*)sg1s)[col - 96] = make_float4(o1[0], o1[1], o1[2], o1[3]);
        ((float4*)sg2s)[col - 96] = make_float4(o2[0], o2[1], o2[2], o2[3]);
    }
    __syncthreads();

    float con = 0.f;
    if (!half && col < 96) {
        float e1v[4], e2v[4], g1[4], g2[4];
        f4arr(((const float4*)eps1)[b * 96 + col], e1v);
        f4arr(((const float4*)eps2)[b * 96 + col], e2v);
        f4arr(((const float4*)sg1s)[col], g1);
        f4arr(((const float4*)sg2s)[col], g2);
        float s1o[4], s2o[4];
        #pragma unroll
        for (int j = 0; j < 4; ++j) {
            float mu1 = z1v[j] + bl;
            float mu2 = z2v[j] + bv;
            float sg1 = g1[j], sg2 = g2[j];
            float e1 = e1v[j], e2 = e2v[j];
            float sv1 = fmaf(sg1, e1, mu1);
            float sv2 = fmaf(sg2, e2, mu2);
            s1o[j] = sv1; s2o[j] = sv2;
            float z12 = (sv1 - mu2) / sg2;
            float z21 = (sv2 - mu1) / sg1;
            con += -0.5f * (e1 * e1 + e2 * e2) + 0.5f * z12 * z12 + 0.5f * z21 * z21;
        }
        ((float4*)s1)[b * 96 + col] = make_float4(s1o[0], s1o[1], s1o[2], s1o[3]);
        ((float4*)s2)[b * 96 + col] = make_float4(s2o[0], s2o[1], s2o[2], s2o[3]);
    }

    #pragma unroll
    for (int m = 1; m < 64; m <<= 1) con += __shfl_xor(con, m);
    __shared__ float pr[6];
    if ((t & 63) == 0) pr[t >> 6] = con;
    __syncthreads();
    if (t == 0) {
        float s = pr[0] + pr[1] + pr[2] + pr[3] + pr[4] + pr[5];
        atomicAdd(&accum[0], s);
    }
}

// ---------------- B: Axb = s1 @ W1x^T + b1 (padded), By = s2 @ W1y^T ----------------
// 32x64 tiles -> 320 blocks; packed <2 x float> math for v_pk_fma_f32.
__global__ __launch_bounds__(256) void k_gemm(
    const float* __restrict__ s1, const float* __restrict__ s2,
    const float* __restrict__ W1, const float* __restrict__ b1,
    float* __restrict__ Axb, float* __restrict__ By)
{
    __shared__ __align__(16) float Ss[32][36];   // [h][b] 32x32
    __shared__ __align__(16) float Ws[32][68];   // [h][k] 32x64
    int z = blockIdx.z;
    const float* S = z ? s2 : s1;
    float* Out = z ? By : Axb;
    int wofs = z ? HIDV : 0;
    int b0 = blockIdx.x * 32;
    int k0 = blockIdx.y * 64;
    int tid = threadIdx.x;
    int srow = tid >> 3, sc = tid & 7;       // S staging: 32 rows x 8 col-groups
    int wrow = tid >> 2, wc = tid & 3;       // W staging: 64 rows x 4 col-groups (x2)
    int krow = k0 + wrow;
    int tx = tid & 15, ty = tid >> 4;

    float4 ps, pw[2];
    auto ld = [&](int hc) {
        ps = *(const float4*)&S[(b0 + srow) * HIDV + hc + sc * 4];
        #pragma unroll
        for (int u = 0; u < 2; ++u)
            pw[u] = (krow < MLPH) ? *(const float4*)&W1[krow * DD + wofs + hc + wc * 4 + u * 16]
                                  : make_float4(0.f, 0.f, 0.f, 0.f);
    };
    ld(0);
    v2f acc[2][2];
    acc[0][0] = (v2f){0.f, 0.f}; acc[0][1] = (v2f){0.f, 0.f};
    acc[1][0] = (v2f){0.f, 0.f}; acc[1][1] = (v2f){0.f, 0.f};

    for (int ch = 0; ch < 12; ++ch) {
        __syncthreads();
        Ss[sc * 4 + 0][srow] = ps.x; Ss[sc * 4 + 1][srow] = ps.y;
        Ss[sc * 4 + 2][srow] = ps.z; Ss[sc * 4 + 3][srow] = ps.w;
        #pragma unroll
        for (int u = 0; u < 2; ++u) {
            int hb = wc * 4 + u * 16;
            Ws[hb + 0][wrow] = pw[u].x; Ws[hb + 1][wrow] = pw[u].y;
            Ws[hb + 2][wrow] = pw[u].z; Ws[hb + 3][wrow] = pw[u].w;
        }
        __syncthreads();
        if (ch < 11) ld((ch + 1) * 32);
        #pragma unroll
        for (int h = 0; h < 32; ++h) {
            v2f sv = *(const v2f*)&Ss[h][ty * 2];
            float4 wq = *(const float4*)&Ws[h][tx * 4];
            v2f w0 = (v2f){wq.x, wq.y};
            v2f w1 = (v2f){wq.z, wq.w};
            v2f s0 = (v2f){sv.x, sv.x};
            v2f s1b = (v2f){sv.y, sv.y};
            acc[0][0] = __builtin_elementwise_fma(s0, w0, acc[0][0]);
            acc[0][1] = __builtin_elementwise_fma(s0, w1, acc[0][1]);
            acc[1][0] = __builtin_elementwise_fma(s1b, w0, acc[1][0]);
            acc[1][1] = __builtin_elementwise_fma(s1b, w1, acc[1][1]);
        }
    }
    #pragma unroll
    for (int i = 0; i < 2; ++i) {
        int bb = b0 + ty * 2 + i;
        float vraw[4] = {acc[i][0].x, acc[i][0].y, acc[i][1].x, acc[i][1].y};
        float o[4];
        #pragma unroll
        for (int j = 0; j < 4; ++j) {
            int k = k0 + tx * 4 + j;
            float v = vraw[j];
            if (!z) v += b1[k < MLPH ? k : 0];
            o[j] = (k < MLPH) ? v : 0.f;
        }
        *(float4*)&Out[bb * MLPP + k0 + tx * 4] = make_float4(o[0], o[1], o[2], o[3]);
    }
}

// ---------------- C: T0 sum ----------------
__global__ void k_t0(const float* __restrict__ Axb, const float* __restrict__ By,
                     const float* __restrict__ W2, const float* __restrict__ b2,
                     float* __restrict__ accum)
{
    int b = blockIdx.x;
    int l = threadIdx.x;  // 64
    float t = 0.f;
    for (int k = l; k < MLPH; k += 64)
        t = fmaf(fmaxf(Axb[b * MLPP + k] + By[b * MLPP + k], 0.f), W2[k], t);
    #pragma unroll
    for (int m = 1; m < 64; m <<= 1) t += __shfl_xor(t, m);
    if (l == 0) atomicAdd(&accum[1], softplusf(t + b2[0]));
}

// ---------------- D: pair kernel, packed math, fused sumexp(T1) ----------------
__global__ __launch_bounds__(256) void k_pairs(
    const float* __restrict__ Axb, const float* __restrict__ By,
    const int* __restrict__ perm, const float* __restrict__ W2,
    const float* __restrict__ b2, float* __restrict__ sumexp)
{
    __shared__ __align__(16) float As[64][68];   // [k][j]
    __shared__ __align__(16) float Bs[64][68];   // [k][i]
    __shared__ float w2s[MLPP];
    int tid = threadIdx.x;
    int j0 = blockIdx.x * 64;
    int i0 = blockIdx.y * 64;
    for (int t = tid; t < MLPP; t += 256) w2s[t] = (t < MLPH) ? W2[t] : 0.f;
    int r = tid >> 2;          // 0..63
    int c4 = tid & 3;
    int tx = tid & 15, ty = tid >> 4;
    int prow = perm[i0 + r];

    float4 pa[4], pb[4];
    auto ld = [&](int kc) {
        #pragma unroll
        for (int u = 0; u < 4; ++u) {
            int kq = (c4 + 4 * u) * 4;   // 0..60
            pa[u] = *(const float4*)&Axb[(j0 + r) * MLPP + kc + kq];
            pb[u] = *(const float4*)&By[prow * MLPP + kc + kq];
        }
    };
    ld(0);
    v2f acc2[4][2];
    #pragma unroll
    for (int c = 0; c < 4; ++c) {
        acc2[c][0] = (v2f){0.f, 0.f};
        acc2[c][1] = (v2f){0.f, 0.f};
    }
    for (int ch = 0; ch < 5; ++ch) {
        __syncthreads();
        #pragma unroll
        for (int u = 0; u < 4; ++u) {
            int kq = (c4 + 4 * u) * 4;
            As[kq + 0][r] = pa[u].x; As[kq + 1][r] = pa[u].y;
            As[kq + 2][r] = pa[u].z; As[kq + 3][r] = pa[u].w;
            Bs[kq + 0][r] = pb[u].x; Bs[kq + 1][r] = pb[u].y;
            Bs[kq + 2][r] = pb[u].z; Bs[kq + 3][r] = pb[u].w;
        }
        __syncthreads();
        if (ch < 4) ld((ch + 1) * 64);
        int kc = ch * 64;
        #pragma unroll
        for (int k = 0; k < 64; ++k) {
            float w = w2s[kc + k];
            v2f wv2 = (v2f){w, w};
            float4 af = *(const float4*)&As[k][tx * 4];
            float4 bf = *(const float4*)&Bs[k][ty * 4];
            v2f a2[2] = { (v2f){af.x, af.y}, (v2f){af.z, af.w} };
            float bs[4] = {bf.x, bf.y, bf.z, bf.w};
            #pragma unroll
            for (int c = 0; c < 4; ++c) {
                v2f bc = (v2f){bs[c], bs[c]};
                #pragma unroll
                for (int d2 = 0; d2 < 2; ++d2) {
                    v2f tv = a2[d2] + bc;
                    tv = __builtin_elementwise_max(tv, (v2f){0.f, 0.f});
                    acc2[c][d2] = __builtin_elementwise_fma(tv, wv2, acc2[c][d2]);
                }
            }
        }
    }
    float b2v = b2[0];
    #pragma unroll
    for (int c = 0; c < 4; ++c) {
        float vv[4] = {acc2[c][0].x, acc2[c][0].y, acc2[c][1].x, acc2[c][1].y};
        float ssum = 0.f;
        #pragma unroll
        for (int d = 0; d < 4; ++d)
            ssum += 1.f + expf(vv[d] + b2v);   // exp(softplus(x)) == 1 + exp(x)
        ssum += __shfl_xor(ssum, 1);
        ssum += __shfl_xor(ssum, 2);
        ssum += __shfl_xor(ssum, 4);
        ssum += __shfl_xor(ssum, 8);
        if (tx == 0) atomicAdd(&sumexp[i0 + ty * 4 + c], ssum);
    }
}

// ---------------- E: final scalar ----------------
__global__ __launch_bounds__(256) void k_final(
    const float* __restrict__ accum, const float* __restrict__ sumexp,
    float* __restrict__ out)
{
    int tid = threadIdx.x;
    float s = 0.f;
    for (int i = tid; i < BB; i += 256) s += logf(sumexp[i]);
    #pragma unroll
    for (int m = 1; m < 64; m <<= 1) s += __shfl_xor(s, m);
    __shared__ float red[4];
    if ((tid & 63) == 0) red[tid >> 6] = s;
    __syncthreads();
    if (tid == 0) {
        float lse_mean = (red[0] + red[1] + red[2] + red[3]) / (float)BB;
        float d_skl = accum[0] / (2.f * (float)BB);
        float t0_mean = accum[1] / (float)BB;
        float lower = t0_mean - (lse_mean - logf((float)BB));
        out[0] = d_skl - lower;
    }
}

extern "C" void kernel_launch(void* const* d_in, const int* in_sizes, int n_in,
                              void* d_out, int out_size, void* d_ws, size_t ws_size,
                              hipStream_t stream)
{
    const float* zl     = (const float*)d_in[0];
    const float* zv     = (const float*)d_in[1];
    const float* fc_l_w = (const float*)d_in[2];
    const float* fc_l_b = (const float*)d_in[3];
    const float* fc_v_w = (const float*)d_in[4];
    const float* fc_v_b = (const float*)d_in[5];
    const float* W1     = (const float*)d_in[6];
    const float* b1     = (const float*)d_in[7];
    const float* W2     = (const float*)d_in[8];
    const float* b2     = (const float*)d_in[9];
    const float* eps1   = (const float*)d_in[10];
    const float* eps2   = (const float*)d_in[11];
    const int*   perm   = (const int*)d_in[12];
    float* out = (float*)d_out;

    float* ws     = (float*)d_ws;
    float* accum  = ws;                    // 16
    float* sumexp = ws + 16;               // 1024
    float* s1     = ws + 16 + BB;          // B*384
    float* s2     = s1 + BB * HIDV;        // B*384
    float* Axb    = s2 + BB * HIDV;        // B*320
    float* By     = Axb + BB * MLPP;       // B*320

    k_init<<<5, 256, 0, stream>>>(ws);
    k_rs<<<BB, 384, 0, stream>>>(zl, zv, fc_l_w, fc_l_b, fc_v_w, fc_v_b,
                                 eps1, eps2, s1, s2, accum);
    k_gemm<<<dim3(32, 5, 2), 256, 0, stream>>>(s1, s2, W1, b1, Axb, By);
    k_t0<<<BB, 64, 0, stream>>>(Axb, By, W2, b2, accum);
    k_pairs<<<dim3(16, 16), 256, 0, stream>>>(Axb, By, perm, W2, b2, sumexp);
    k_final<<<1, 256, 0, stream>>>(accum, sumexp, out);
}

// Round 6
// 310.565 us; speedup vs baseline: 1.0134x; 1.0066x over previous
//
#include <hip/hip_runtime.h>
#include <math.h>

#define BB   1024
#define DD   768
#define HIDV 384
#define MLPH 300
#define MLPP 320   // padded to multiple of 64

typedef float v2f __attribute__((ext_vector_type(2)));

typedef const __attribute__((address_space(1))) void* gas_t;
typedef __attribute__((address_space(3))) void* las_t;

__device__ __forceinline__ float softplusf(float x) {
    return (x > 20.f) ? x : log1pf(expf(x));
}

__device__ __forceinline__ void f4arr(float4 v, float* o) {
    o[0] = v.x; o[1] = v.y; o[2] = v.z; o[3] = v.w;
}

// async global->LDS, 16B per lane. lds dst = wave-uniform base + lane*16 (HW).
__device__ __forceinline__ void cp16(const float* g, float* l) {
    __builtin_amdgcn_global_load_lds((gas_t)g, (las_t)l, 16, 0, 0);
}

#define WAITVM(n)  asm volatile("s_waitcnt vmcnt(" #n ")" ::: "memory")
#define WAITLGKM() asm volatile("s_waitcnt lgkmcnt(0)" ::: "memory")

// ---------------- init: zero accumulators (accum[16] + sumexp[1024]) ----------------
__global__ void k_init(float* __restrict__ ws) {
    int i = blockIdx.x * 256 + threadIdx.x;
    if (i < 16 + BB) ws[i] = 0.f;
}

// ---------------- A: fused z-reduce + sample + KL, async-LDS staging ----------------
// One block (256 thr, 4 waves) per row. Wave w privately owns s-rows:
//   zl rows w*5..w*5+4 (A-slot 3 rows + B-slot 2 rows),
//   zv rows w*9..w*9+8 (A 3 + B 2 + A 3 + B 1), ping-pong through LDS.
// No barriers in the staging pipeline: slots are wave-private; ordering is
// enforced by explicit s_waitcnt vmcnt(N) (async loads complete in order).
// ~15 KB in flight per wave at all times, independent of VGPR allocation.
__global__ __launch_bounds__(256) void k_rs(
    const float* __restrict__ zl, const float* __restrict__ zv,
    const float* __restrict__ wl, const float* __restrict__ blp,
    const float* __restrict__ wv, const float* __restrict__ bvp,
    const float* __restrict__ eps1, const float* __restrict__ eps2,
    float* __restrict__ s1, float* __restrict__ s2, float* __restrict__ accum)
{
    __shared__ float LA[9216];   // 4 waves x 3-row slots (2304 floats)
    __shared__ float LB[6144];   // 4 waves x 2-row slots (1536 floats)
    int tid = threadIdx.x, w = tid >> 6, l = tid & 63, b = blockIdx.x;

    const float* zlb = zl + b * 15360;          // 20*768
    const float* zvb = zv + b * 27648;          // 36*768
    const float* gA0 = zlb + (w * 5 + 0) * 768 + l * 4;
    const float* gB0 = zlb + (w * 5 + 3) * 768 + l * 4;
    const float* gA1 = zvb + (w * 9 + 0) * 768 + l * 4;
    const float* gB1 = zvb + (w * 9 + 3) * 768 + l * 4;
    const float* gA2 = zvb + (w * 9 + 5) * 768 + l * 4;
    const float* gB2 = zvb + (w * 9 + 8) * 768 + l * 4;
    float* sA = LA + w * 2304;
    float* sB = LB + w * 1536;

    // preload weights BEFORE any async issue, then drain vmcnt so the
    // hand-counted vmcnt(N) waits below see only async loads.
    float wl_r[5], wv_r[9];
    #pragma unroll
    for (int r = 0; r < 5; ++r) wl_r[r] = wl[w * 5 + r];
    #pragma unroll
    for (int r = 0; r < 9; ++r) wv_r[r] = wv[w * 9 + r];
    WAITVM(0);

    float a1[3][4] = {{0.f}}, a2[3][4] = {{0.f}};

    // issue A0 (zl rows 0..2, 9 chunks) + B0 (zl rows 3..4, 6 chunks)
    #pragma unroll
    for (int r = 0; r < 3; ++r)
        #pragma unroll
        for (int c = 0; c < 3; ++c)
            cp16(gA0 + r * 768 + c * 256, sA + r * 768 + c * 256);
    #pragma unroll
    for (int r = 0; r < 2; ++r)
        #pragma unroll
        for (int c = 0; c < 3; ++c)
            cp16(gB0 + r * 768 + c * 256, sB + r * 768 + c * 256);

    WAITVM(6);   // A0 landed (B0's 6 may remain)
    #pragma unroll
    for (int r = 0; r < 3; ++r) {
        float ws_ = wl_r[r];
        #pragma unroll
        for (int c = 0; c < 3; ++c) {
            float v[4]; f4arr(*(const float4*)(sA + r * 768 + c * 256 + l * 4), v);
            #pragma unroll
            for (int j = 0; j < 4; ++j) a1[c][j] = fmaf(v[j], ws_, a1[c][j]);
        }
    }
    WAITLGKM();
    // issue A1 (zv rows 0..2)
    #pragma unroll
    for (int r = 0; r < 3; ++r)
        #pragma unroll
        for (int c = 0; c < 3; ++c)
            cp16(gA1 + r * 768 + c * 256, sA + r * 768 + c * 256);

    WAITVM(9);   // B0 landed (A1's 9 remain)
    #pragma unroll
    for (int r = 0; r < 2; ++r) {
        float ws_ = wl_r[3 + r];
        #pragma unroll
        for (int c = 0; c < 3; ++c) {
            float v[4]; f4arr(*(const float4*)(sB + r * 768 + c * 256 + l * 4), v);
            #pragma unroll
            for (int j = 0; j < 4; ++j) a1[c][j] = fmaf(v[j], ws_, a1[c][j]);
        }
    }
    WAITLGKM();
    // issue B1 (zv rows 3..4)
    #pragma unroll
    for (int r = 0; r < 2; ++r)
        #pragma unroll
        for (int c = 0; c < 3; ++c)
            cp16(gB1 + r * 768 + c * 256, sB + r * 768 + c * 256);

    WAITVM(6);   // A1 landed
    #pragma unroll
    for (int r = 0; r < 3; ++r) {
        float ws_ = wv_r[r];
        #pragma unroll
        for (int c = 0; c < 3; ++c) {
            float v[4]; f4arr(*(const float4*)(sA + r * 768 + c * 256 + l * 4), v);
            #pragma unroll
            for (int j = 0; j < 4; ++j) a2[c][j] = fmaf(v[j], ws_, a2[c][j]);
        }
    }
    WAITLGKM();
    // issue A2 (zv rows 5..7)
    #pragma unroll
    for (int r = 0; r < 3; ++r)
        #pragma unroll
        for (int c = 0; c < 3; ++c)
            cp16(gA2 + r * 768 + c * 256, sA + r * 768 + c * 256);

    WAITVM(9);   // B1 landed
    #pragma unroll
    for (int r = 0; r < 2; ++r) {
        float ws_ = wv_r[3 + r];
        #pragma unroll
        for (int c = 0; c < 3; ++c) {
            float v[4]; f4arr(*(const float4*)(sB + r * 768 + c * 256 + l * 4), v);
            #pragma unroll
            for (int j = 0; j < 4; ++j) a2[c][j] = fmaf(v[j], ws_, a2[c][j]);
        }
    }
    WAITLGKM();
    // issue B2 (zv row 8, 3 chunks)
    #pragma unroll
    for (int c = 0; c < 3; ++c)
        cp16(gB2 + c * 256, sB + c * 256);

    WAITVM(3);   // A2 landed
    #pragma unroll
    for (int r = 0; r < 3; ++r) {
        float ws_ = wv_r[5 + r];
        #pragma unroll
        for (int c = 0; c < 3; ++c) {
            float v[4]; f4arr(*(const float4*)(sA + r * 768 + c * 256 + l * 4), v);
            #pragma unroll
            for (int j = 0; j < 4; ++j) a2[c][j] = fmaf(v[j], ws_, a2[c][j]);
        }
    }
    WAITVM(0);   // B2 landed
    {
        float ws_ = wv_r[8];
        #pragma unroll
        for (int c = 0; c < 3; ++c) {
            float v[4]; f4arr(*(const float4*)(sB + c * 256 + l * 4), v);
            #pragma unroll
            for (int j = 0; j < 4; ++j) a2[c][j] = fmaf(v[j], ws_, a2[c][j]);
        }
    }

    // write per-wave partials into own A-slot: z1 at [0,768), z2 at [768,1536)
    #pragma unroll
    for (int c = 0; c < 3; ++c) {
        *(float4*)(LA + w * 2304 + (c * 64 + l) * 4) =
            make_float4(a1[c][0], a1[c][1], a1[c][2], a1[c][3]);
        *(float4*)(LA + w * 2304 + 768 + (c * 64 + l) * 4) =
            make_float4(a2[c][0], a2[c][1], a2[c][2], a2[c][3]);
    }
    __syncthreads();

    float bl = blp[0], bv = bvp[0];
    float z1v[4] = {0,0,0,0}, z2v[4] = {0,0,0,0};
    if (tid < 192) {
        #pragma unroll
        for (int w2 = 0; w2 < 4; ++w2) {
            float q1[4], q2[4];
            f4arr(*(const float4*)(LA + w2 * 2304 + tid * 4), q1);
            f4arr(*(const float4*)(LA + w2 * 2304 + 768 + tid * 4), q2);
            #pragma unroll
            for (int j = 0; j < 4; ++j) { z1v[j] += q1[j]; z2v[j] += q2[j]; }
        }
    }
    __syncthreads();   // LB free for sg exchange
    if (tid >= 96 && tid < 192) {
        float o1[4], o2[4];
        #pragma unroll
        for (int j = 0; j < 4; ++j) {
            o1[j] = softplusf(z1v[j] + bl) + 1e-7f;
            o2[j] = softplusf(z2v[j] + bv) + 1e-7f;
        }
        *(float4*)(LB + (tid - 96) * 4)       = make_float4(o1[0], o1[1], o1[2], o1[3]);
        *(float4*)(LB + 384 + (tid - 96) * 4) = make_float4(o2[0], o2[1], o2[2], o2[3]);
    }
    __syncthreads();

    float con = 0.f;
    if (tid < 96) {
        float e1v[4], e2v[4], g1[4], g2[4];
        f4arr(((const float4*)eps1)[b * 96 + tid], e1v);
        f4arr(((const float4*)eps2)[b * 96 + tid], e2v);
        f4arr(*(const float4*)(LB + tid * 4), g1);
        f4arr(*(const float4*)(LB + 384 + tid * 4), g2);
        float s1o[4], s2o[4];
        #pragma unroll
        for (int j = 0; j < 4; ++j) {
            float mu1 = z1v[j] + bl;
            float mu2 = z2v[j] + bv;
            float sg1 = g1[j], sg2 = g2[j];
            float e1 = e1v[j], e2 = e2v[j];
            float sv1 = fmaf(sg1, e1, mu1);
            float sv2 = fmaf(sg2, e2, mu2);
            s1o[j] = sv1; s2o[j] = sv2;
            float z12 = (sv1 - mu2) / sg2;
            float z21 = (sv2 - mu1) / sg1;
            con += -0.5f * (e1 * e1 + e2 * e2) + 0.5f * z12 * z12 + 0.5f * z21 * z21;
        }
        ((float4*)s1)[b * 96 + tid] = make_float4(s1o[0], s1o[1], s1o[2], s1o[3]);
        ((float4*)s2)[b * 96 + tid] = make_float4(s2o[0], s2o[1], s2o[2], s2o[3]);
    }

    #pragma unroll
    for (int m = 1; m < 64; m <<= 1) con += __shfl_xor(con, m);
    __shared__ float pr[4];
    if ((tid & 63) == 0) pr[tid >> 6] = con;
    __syncthreads();
    if (tid == 0) atomicAdd(&accum[0], pr[0] + pr[1] + pr[2] + pr[3]);
}

// ---------------- B: Axb = s1 @ W1x^T + b1 (padded), By = s2 @ W1y^T ----------------
__global__ __launch_bounds__(256) void k_gemm(
    const float* __restrict__ s1, const float* __restrict__ s2,
    const float* __restrict__ W1, const float* __restrict__ b1,
    float* __restrict__ Axb, float* __restrict__ By)
{
    __shared__ __align__(16) float Ss[32][36];   // [h][b] 32x32
    __shared__ __align__(16) float Ws[32][68];   // [h][k] 32x64
    int z = blockIdx.z;
    const float* S = z ? s2 : s1;
    float* Out = z ? By : Axb;
    int wofs = z ? HIDV : 0;
    int b0 = blockIdx.x * 32;
    int k0 = blockIdx.y * 64;
    int tid = threadIdx.x;
    int srow = tid >> 3, sc = tid & 7;
    int wrow = tid >> 2, wc = tid & 3;
    int krow = k0 + wrow;
    int tx = tid & 15, ty = tid >> 4;

    float4 ps, pw[2];
    auto ld = [&](int hc) {
        ps = *(const float4*)&S[(b0 + srow) * HIDV + hc + sc * 4];
        #pragma unroll
        for (int u = 0; u < 2; ++u)
            pw[u] = (krow < MLPH) ? *(const float4*)&W1[krow * DD + wofs + hc + wc * 4 + u * 16]
                                  : make_float4(0.f, 0.f, 0.f, 0.f);
    };
    ld(0);
    v2f acc[2][2];
    acc[0][0] = (v2f){0.f, 0.f}; acc[0][1] = (v2f){0.f, 0.f};
    acc[1][0] = (v2f){0.f, 0.f}; acc[1][1] = (v2f){0.f, 0.f};

    for (int ch = 0; ch < 12; ++ch) {
        __syncthreads();
        Ss[sc * 4 + 0][srow] = ps.x; Ss[sc * 4 + 1][srow] = ps.y;
        Ss[sc * 4 + 2][srow] = ps.z; Ss[sc * 4 + 3][srow] = ps.w;
        #pragma unroll
        for (int u = 0; u < 2; ++u) {
            int hb = wc * 4 + u * 16;
            Ws[hb + 0][wrow] = pw[u].x; Ws[hb + 1][wrow] = pw[u].y;
            Ws[hb + 2][wrow] = pw[u].z; Ws[hb + 3][wrow] = pw[u].w;
        }
        __syncthreads();
        if (ch < 11) ld((ch + 1) * 32);
        #pragma unroll
        for (int h = 0; h < 32; ++h) {
            v2f sv = *(const v2f*)&Ss[h][ty * 2];
            float4 wq = *(const float4*)&Ws[h][tx * 4];
            v2f w0 = (v2f){wq.x, wq.y};
            v2f w1 = (v2f){wq.z, wq.w};
            v2f s0 = (v2f){sv.x, sv.x};
            v2f s1b = (v2f){sv.y, sv.y};
            acc[0][0] = __builtin_elementwise_fma(s0, w0, acc[0][0]);
            acc[0][1] = __builtin_elementwise_fma(s0, w1, acc[0][1]);
            acc[1][0] = __builtin_elementwise_fma(s1b, w0, acc[1][0]);
            acc[1][1] = __builtin_elementwise_fma(s1b, w1, acc[1][1]);
        }
    }
    #pragma unroll
    for (int i = 0; i < 2; ++i) {
        int bb = b0 + ty * 2 + i;
        float vraw[4] = {acc[i][0].x, acc[i][0].y, acc[i][1].x, acc[i][1].y};
        float o[4];
        #pragma unroll
        for (int j = 0; j < 4; ++j) {
            int k = k0 + tx * 4 + j;
            float v = vraw[j];
            if (!z) v += b1[k < MLPH ? k : 0];
            o[j] = (k < MLPH) ? v : 0.f;
        }
        *(float4*)&Out[bb * MLPP + k0 + tx * 4] = make_float4(o[0], o[1], o[2], o[3]);
    }
}

// ---------------- C: T0 sum ----------------
__global__ void k_t0(const float* __restrict__ Axb, const float* __restrict__ By,
                     const float* __restrict__ W2, const float* __restrict__ b2,
                     float* __restrict__ accum)
{
    int b = blockIdx.x;
    int l = threadIdx.x;  // 64
    float t = 0.f;
    for (int k = l; k < MLPH; k += 64)
        t = fmaf(fmaxf(Axb[b * MLPP + k] + By[b * MLPP + k], 0.f), W2[k], t);
    #pragma unroll
    for (int m = 1; m < 64; m <<= 1) t += __shfl_xor(t, m);
    if (l == 0) atomicAdd(&accum[1], softplusf(t + b2[0]));
}

// ---------------- D: pair kernel, packed math, fused sumexp(T1) ----------------
__global__ __launch_bounds__(256) void k_pairs(
    const float* __restrict__ Axb, const float* __restrict__ By,
    const int* __restrict__ perm, const float* __restrict__ W2,
    const float* __restrict__ b2, float* __restrict__ sumexp)
{
    __shared__ __align__(16) float As[64][68];   // [k][j]
    __shared__ __align__(16) float Bs[64][68];   // [k][i]
    __shared__ float w2s[MLPP];
    int tid = threadIdx.x;
    int j0 = blockIdx.x * 64;
    int i0 = blockIdx.y * 64;
    for (int t = tid; t < MLPP; t += 256) w2s[t] = (t < MLPH) ? W2[t] : 0.f;
    int r = tid >> 2;          // 0..63
    int c4 = tid & 3;
    int tx = tid & 15, ty = tid >> 4;
    int prow = perm[i0 + r];

    float4 pa[4], pb[4];
    auto ld = [&](int kc) {
        #pragma unroll
        for (int u = 0; u < 4; ++u) {
            int kq = (c4 + 4 * u) * 4;   // 0..60
            pa[u] = *(const float4*)&Axb[(j0 + r) * MLPP + kc + kq];
            pb[u] = *(const float4*)&By[prow * MLPP + kc + kq];
        }
    };
    ld(0);
    v2f acc2[4][2];
    #pragma unroll
    for (int c = 0; c < 4; ++c) {
        acc2[c][0] = (v2f){0.f, 0.f};
        acc2[c][1] = (v2f){0.f, 0.f};
    }
    for (int ch = 0; ch < 5; ++ch) {
        __syncthreads();
        #pragma unroll
        for (int u = 0; u < 4; ++u) {
            int kq = (c4 + 4 * u) * 4;
            As[kq + 0][r] = pa[u].x; As[kq + 1][r] = pa[u].y;
            As[kq + 2][r] = pa[u].z; As[kq + 3][r] = pa[u].w;
            Bs[kq + 0][r] = pb[u].x; Bs[kq + 1][r] = pb[u].y;
            Bs[kq + 2][r] = pb[u].z; Bs[kq + 3][r] = pb[u].w;
        }
        __syncthreads();
        if (ch < 4) ld((ch + 1) * 64);
        int kc = ch * 64;
        #pragma unroll
        for (int k = 0; k < 64; ++k) {
            float w = w2s[kc + k];
            v2f wv2 = (v2f){w, w};
            float4 af = *(const float4*)&As[k][tx * 4];
            float4 bf = *(const float4*)&Bs[k][ty * 4];
            v2f a2[2] = { (v2f){af.x, af.y}, (v2f){af.z, af.w} };
            float bs[4] = {bf.x, bf.y, bf.z, bf.w};
            #pragma unroll
            for (int c = 0; c < 4; ++c) {
                v2f bc = (v2f){bs[c], bs[c]};
                #pragma unroll
                for (int d2 = 0; d2 < 2; ++d2) {
                    v2f tv = a2[d2] + bc;
                    tv = __builtin_elementwise_max(tv, (v2f){0.f, 0.f});
                    acc2[c][d2] = __builtin_elementwise_fma(tv, wv2, acc2[c][d2]);
                }
            }
        }
    }
    float b2v = b2[0];
    #pragma unroll
    for (int c = 0; c < 4; ++c) {
        float vv[4] = {acc2[c][0].x, acc2[c][0].y, acc2[c][1].x, acc2[c][1].y};
        float ssum = 0.f;
        #pragma unroll
        for (int d = 0; d < 4; ++d)
            ssum += 1.f + expf(vv[d] + b2v);   // exp(softplus(x)) == 1 + exp(x)
        ssum += __shfl_xor(ssum, 1);
        ssum += __shfl_xor(ssum, 2);
        ssum += __shfl_xor(ssum, 4);
        ssum += __shfl_xor(ssum, 8);
        if (tx == 0) atomicAdd(&sumexp[i0 + ty * 4 + c], ssum);
    }
}

// ---------------- E: final scalar ----------------
__global__ __launch_bounds__(256) void k_final(
    const float* __restrict__ accum, const float* __restrict__ sumexp,
    float* __restrict__ out)
{
    int tid = threadIdx.x;
    float s = 0.f;
    for (int i = tid; i < BB; i += 256) s += logf(sumexp[i]);
    #pragma unroll
    for (int m = 1; m < 64; m <<= 1) s += __shfl_xor(s, m);
    __shared__ float red[4];
    if ((tid & 63) == 0) red[tid >> 6] = s;
    __syncthreads();
    if (tid == 0) {
        float lse_mean = (red[0] + red[1] + red[2] + red[3]) / (float)BB;
        float d_skl = accum[0] / (2.f * (float)BB);
        float t0_mean = accum[1] / (float)BB;
        float lower = t0_mean - (lse_mean - logf((float)BB));
        out[0] = d_skl - lower;
    }
}

extern "C" void kernel_launch(void* const* d_in, const int* in_sizes, int n_in,
                              void* d_out, int out_size, void* d_ws, size_t ws_size,
                              hipStream_t stream)
{
    const float* zl     = (const float*)d_in[0];
    const float* zv     = (const float*)d_in[1];
    const float* fc_l_w = (const float*)d_in[2];
    const float* fc_l_b = (const float*)d_in[3];
    const float* fc_v_w = (const float*)d_in[4];
    const float* fc_v_b = (const float*)d_in[5];
    const float* W1     = (const float*)d_in[6];
    const float* b1     = (const float*)d_in[7];
    const float* W2     = (const float*)d_in[8];
    const float* b2     = (const float*)d_in[9];
    const float* eps1   = (const float*)d_in[10];
    const float* eps2   = (const float*)d_in[11];
    const int*   perm   = (const int*)d_in[12];
    float* out = (float*)d_out;

    float* ws     = (float*)d_ws;
    float* accum  = ws;                    // 16
    float* sumexp = ws + 16;               // 1024
    float* s1     = ws + 16 + BB;          // B*384
    float* s2     = s1 + BB * HIDV;        // B*384
    float* Axb    = s2 + BB * HIDV;        // B*320
    float* By     = Axb + BB * MLPP;       // B*320

    k_init<<<5, 256, 0, stream>>>(ws);
    k_rs<<<BB, 256, 0, stream>>>(zl, zv, fc_l_w, fc_l_b, fc_v_w, fc_v_b,
                                 eps1, eps2, s1, s2, accum);
    k_gemm<<<dim3(32, 5, 2), 256, 0, stream>>>(s1, s2, W1, b1, Axb, By);
    k_t0<<<BB, 64, 0, stream>>>(Axb, By, W2, b2, accum);
    k_pairs<<<dim3(16, 16), 256, 0, stream>>>(Axb, By, perm, W2, b2, sumexp);
    k_final<<<1, 256, 0, stream>>>(accum, sumexp, out);
}